// Round 11
// baseline (4440.039 us; speedup 1.0000x reference)
//
#include <hip/hip_runtime.h>
#include <math.h>

#define Bz 32
#define Lz 2048
#define Iz 64
#define Hz 512
#define HALFz 256
#define DTz 0.05f
#define NMEM 8
#define TPB 512

typedef unsigned long long u64;

__device__ __forceinline__ bool tagok(u64 v, unsigned tag) {
  u64 want = (u64)tag | ((u64)tag << 48);
  return ((v ^ want) & 0xFFFF00000000FFFFull) == 0ull;
}
__device__ __forceinline__ u64 packv(float f, unsigned tag) {
  return (u64)tag | ((u64)__float_as_uint(f) << 16) | ((u64)tag << 48);
}
__device__ __forceinline__ float unpackv(u64 v) {
  return __uint_as_float((unsigned)(v >> 16));
}

// ============= single-buffer pipelined-poll kernel (primary) =============
// R6 topology (proven 3412us): 8 blocks/batch, weights register-resident,
// thread u polls col u, owners (l<8) publish, RFF in poll shadow, 1 barrier.
// R10 evidence: cross-CU visibility is MALL-only on gfx950 (no L2 path even
// same-XCD) -> exchange RTT ~2500cy is a HW floor. This round trims overhead:
//  - Y-only exchange (X path proven dead): single atomic publish per value.
//  - pipelined polling: 2 loads in flight, positional s_waitcnt vmcnt(1)
//    (vmcnt retires in issue order) -> retry quantum ~350cy not ~700cy.
//    Spec load issued BEFORE the publish store so it's the oldest vm op.
//  - weakened barrier: s_waitcnt lgkmcnt(0) + s_barrier (no vmcnt drain; the
//    once-per-step vmcnt(0) drain happens before reissue where all vm ops are
//    long-completed, keeping pending-load register lifetimes safe).
// Parity-2 reuse safety is the R6 transitive-barrier argument (program order
// + publish visibility), unaffected by the weakened barrier.
// NOTE (R5 bug): rff_acc's shfl chain fully reduces wx into every lane of the
// 16-lane kseg group -> zc/zs complete per-lane; never re-reduce them.
__global__ __launch_bounds__(TPB, 2) void coesn_y1(
    const float* __restrict__ x, const float* __restrict__ x2h,
    const float* __restrict__ h2h, const float* __restrict__ bias,
    const float* __restrict__ gam, const float* __restrict__ eps,
    const float* __restrict__ W_rff, u64* __restrict__ Eb,
    float* __restrict__ out) {
  __shared__ __align__(16) float hyf[2][Hz];   // swizzled hy double buffer
  __shared__ __align__(16) float xb[2][Iz];    // x_t double buffer

  const int b  = blockIdx.x & 31;
  const int m  = blockIdx.x >> 5;
  const int u  = threadIdx.x;
  const int w  = u >> 6;          // wave id; owner-member of global col u
  const int l  = u & 63;
  const int c0 = m * 64;
  const int j  = ((l & 1) << 2) | (l & 2) | ((l >> 2) & 1);  // fold col map
  const int mycol = c0 + w * 8 + j;
  const int rloc = u >> 4, kseg = u & 15;

  // ---- weights into registers (one-time) ----
  float wreg[8][8];   // h2h[8l+r][c0+8w+c]
  {
    const float* hrow = h2h + (size_t)(8 * l) * Hz + c0 + 8 * w;
    #pragma unroll
    for (int r = 0; r < 8; ++r) {
      float4 v0 = *(const float4*)(hrow + (size_t)r * Hz);
      float4 v1 = *(const float4*)(hrow + (size_t)r * Hz + 4);
      wreg[r][0] = v0.x; wreg[r][1] = v0.y; wreg[r][2] = v0.z; wreg[r][3] = v0.w;
      wreg[r][4] = v1.x; wreg[r][5] = v1.y; wreg[r][6] = v1.z; wreg[r][7] = v1.w;
    }
  }
  float xreg[8];      // x2h[l][c0+8w+c]
  {
    float4 v0 = *(const float4*)(x2h + (size_t)l * Hz + c0 + 8 * w);
    float4 v1 = *(const float4*)(x2h + (size_t)l * Hz + c0 + 8 * w + 4);
    xreg[0] = v0.x; xreg[1] = v0.y; xreg[2] = v0.z; xreg[3] = v0.w;
    xreg[4] = v1.x; xreg[5] = v1.y; xreg[6] = v1.z; xreg[7] = v1.w;
  }
  float wr[32];       // W_rff[m*32+rloc][kseg*32 ..)
  {
    const float* wp = W_rff + (size_t)(m * 32 + rloc) * Hz + kseg * 32;
    #pragma unroll
    for (int i = 0; i < 32; ++i) wr[i] = wp[i];
  }

  const float bu = bias[mycol];
  const float gu = gam[mycol];
  const float eu = eps[mycol];
  float hy = 0.f, hz = 0.f, zc = 0.f, zs = 0.f;
  u64 v0 = 0, v1 = 0;          // pipelined poll slots (loop-carried)
  hyf[0][u] = 0.f;
  if (u < 16) ((float4*)xb[0])[u] = ((const float4*)(x + (size_t)b * Lz * Iz))[u];
  __syncthreads();

  auto rff_acc = [&](const float* hsrc) {
    float acc = 0.f;
    const float4* hp = (const float4*)hsrc;
    #pragma unroll
    for (int i = 0; i < 8; ++i) {
      int q = kseg * 8 + i;
      float4 h4 = hp[q ^ ((q >> 3) & 7)];
      acc = fmaf(h4.x, wr[4 * i], acc);
      acc = fmaf(h4.y, wr[4 * i + 1], acc);
      acc = fmaf(h4.z, wr[4 * i + 2], acc);
      acc = fmaf(h4.w, wr[4 * i + 3], acc);
    }
    acc += __shfl_xor(acc, 1); acc += __shfl_xor(acc, 2);
    acc += __shfl_xor(acc, 4); acc += __shfl_xor(acc, 8);
    float sv, cv;
    __sincosf(acc, &sv, &cv);
    zc += cv; zs += sv;   // complete per-lane across the 16-lane group
  };

  for (int t = 0; t < Lz; ++t) {
    const int cur = t & 1, nxt = cur ^ 1;

    // ---- x(t+1) prefetch ----
    if (u < 16 && t + 1 < Lz)
      ((float4*)xb[nxt])[u] =
          ((const float4*)(x + ((size_t)b * Lz + (t + 1)) * Iz))[u];

    __builtin_amdgcn_s_setprio(1);
    // ---- matvec: lane covers K-rows [8l,8l+8) for cols c0+8w..+8 ----
    float hv[8];
    {
      const float4* hp = (const float4*)hyf[cur];
      int q0 = 2 * l, q1 = 2 * l + 1;
      float4 h0 = hp[q0 ^ ((q0 >> 3) & 7)];
      float4 h1 = hp[q1 ^ ((q1 >> 3) & 7)];
      hv[0] = h0.x; hv[1] = h0.y; hv[2] = h0.z; hv[3] = h0.w;
      hv[4] = h1.x; hv[5] = h1.y; hv[6] = h1.z; hv[7] = h1.w;
    }
    float a[8] = {0.f,0.f,0.f,0.f,0.f,0.f,0.f,0.f};
    #pragma unroll
    for (int r = 0; r < 8; ++r) {
      float h = hv[r];
      #pragma unroll
      for (int c = 0; c < 8; ++c) a[c] = fmaf(h, wreg[r][c], a[c]);
    }
    {
      float xv = xb[cur][l];
      #pragma unroll
      for (int c = 0; c < 8; ++c) a[c] = fmaf(xv, xreg[c], a[c]);
    }
    // ---- 10-shuffle fold: lane ends with full sum for col j(l) ----
    #pragma unroll
    for (int i = 0; i < 4; ++i) {
      float snd = (l & 1) ? a[i] : a[i + 4];
      float rcv = __shfl_xor(snd, 1);
      a[i] = ((l & 1) ? a[i + 4] : a[i]) + rcv;
    }
    #pragma unroll
    for (int i = 0; i < 2; ++i) {
      float snd = (l & 2) ? a[i] : a[i + 2];
      float rcv = __shfl_xor(snd, 2);
      a[i] = ((l & 2) ? a[i + 2] : a[i]) + rcv;
    }
    float s;
    {
      float snd = (l & 4) ? a[0] : a[1];
      float rcv = __shfl_xor(snd, 4);
      s = ((l & 4) ? a[1] : a[0]) + rcv;
    }
    s += __shfl_xor(s, 8); s += __shfl_xor(s, 16); s += __shfl_xor(s, 32);

    // ---- state update ----
    s += bu;
    float e2 = __expf(s + s);
    float pre = 1.f - 2.f * __builtin_amdgcn_rcpf(e2 + 1.f);   // fast tanh
    float hzn = fmaf(DTz, pre - gu * hy - eu * hz, hz);
    hy = fmaf(DTz, hzn, hy);
    hz = hzn;
    __builtin_amdgcn_s_setprio(0);

    const unsigned tag = (unsigned)(t + 1);
    u64* EA = Eb + ((size_t)nxt * Bz + b) * Hz;

    // ---- drain leftover vm ops (all issued >=400cy ago -> ~free). Keeps
    //      pending-poll register lifetimes safe before re-binding v0/v1. ----
    asm volatile("s_waitcnt vmcnt(0)" ::: "memory");

    // ---- spec poll issue FIRST (oldest vm op -> vmcnt(1) targets it) ----
    if (w != m)
      asm volatile("global_load_dwordx2 %0, %1, off sc0 sc1"
                   : "=&v"(v0) : "v"(EA + u) : "memory");

    // ---- publish hy(t+1): single agent-atomic store (MALL) ----
    if (l < 8) {
      u64 pv = packv(hy, tag);
      __hip_atomic_store(EA + mycol, pv, __ATOMIC_RELAXED,
                         __HIP_MEMORY_SCOPE_AGENT);
      int q = mycol >> 2;
      hyf[nxt][((q ^ ((q >> 3) & 7)) << 2) | (mycol & 3)] = hy;   // local cols
    }

    // ---- RFF on hy(t) in the exchange shadow ----
    if (t > 0) rff_acc(hyf[cur]);

    // ---- pipelined validate: 2 loads in flight, vmcnt(1) positional ----
    if (w != m) {
      asm volatile("global_load_dwordx2 %0, %1, off sc0 sc1"
                   : "=&v"(v1) : "v"(EA + u) : "memory");
      u64 val; long it = 0; int sel = 0;
      for (;;) {
        u64 got;
        if (sel == 0) {
          asm volatile("s_waitcnt vmcnt(1)" : "+v"(v0) :: "memory");
          got = v0;
          if (!tagok(got, tag))
            asm volatile("global_load_dwordx2 %0, %1, off sc0 sc1"
                         : "=&v"(v0) : "v"(EA + u) : "memory");
        } else {
          asm volatile("s_waitcnt vmcnt(1)" : "+v"(v1) :: "memory");
          got = v1;
          if (!tagok(got, tag))
            asm volatile("global_load_dwordx2 %0, %1, off sc0 sc1"
                         : "=&v"(v1) : "v"(EA + u) : "memory");
        }
        if (tagok(got, tag)) { val = got; break; }
        sel ^= 1;
        if (++it > (1 << 21)) { val = got; break; }   // safety bail
      }
      int q = u >> 2;
      hyf[nxt][((q ^ ((q >> 3) & 7)) << 2) | (u & 3)] = unpackv(val);
    }

    // ---- weakened barrier: order LDS only; no vmcnt drain ----
    asm volatile("s_waitcnt lgkmcnt(0)" ::: "memory");
    __builtin_amdgcn_s_barrier();
  }

  // drain any pending poll load, keep v0/v1 alive until here
  asm volatile("s_waitcnt vmcnt(0)" ::: "memory");
  asm volatile("" :: "v"(v0), "v"(v1));

  // final RFF term on hy(Lz) (loop covered hy(1)..hy(Lz-1)); Lz even -> [0]
  rff_acc(hyf[0]);

  if (l < 8) out[(size_t)Bz * Hz + (size_t)b * Hz + mycol] = hy;
  if (kseg == 0) {
    const float sc = 0.0625f / 2048.f;   // (1/sqrt(256)) / L
    out[(size_t)b * Hz + m * 32 + rloc] = zc * sc;
    out[(size_t)b * Hz + HALFz + m * 32 + rloc] = zs * sc;
  }
}

// ================= secondary: proven R6 kernel (3412us) =================
__global__ __launch_bounds__(TPB, 2) void coesn_x2(
    const float* __restrict__ x, const float* __restrict__ x2h,
    const float* __restrict__ h2h, const float* __restrict__ bias,
    const float* __restrict__ gam, const float* __restrict__ eps,
    const float* __restrict__ W_rff, u64* __restrict__ Xb,
    u64* __restrict__ Yb, float* __restrict__ out) {
  __shared__ __align__(16) float hyf[2][Hz];
  __shared__ __align__(16) float xb[2][Iz];

  const int b  = blockIdx.x & 31;
  const int m  = blockIdx.x >> 5;
  const int u  = threadIdx.x;
  const int w  = u >> 6;
  const int l  = u & 63;
  const int c0 = m * 64;
  const int j  = ((l & 1) << 2) | (l & 2) | ((l >> 2) & 1);
  const int mycol = c0 + w * 8 + j;
  const int rloc = u >> 4, kseg = u & 15;

  float wreg[8][8];
  {
    const float* hrow = h2h + (size_t)(8 * l) * Hz + c0 + 8 * w;
    #pragma unroll
    for (int r = 0; r < 8; ++r) {
      float4 v0 = *(const float4*)(hrow + (size_t)r * Hz);
      float4 v1 = *(const float4*)(hrow + (size_t)r * Hz + 4);
      wreg[r][0] = v0.x; wreg[r][1] = v0.y; wreg[r][2] = v0.z; wreg[r][3] = v0.w;
      wreg[r][4] = v1.x; wreg[r][5] = v1.y; wreg[r][6] = v1.z; wreg[r][7] = v1.w;
    }
  }
  float xreg[8];
  {
    float4 v0 = *(const float4*)(x2h + (size_t)l * Hz + c0 + 8 * w);
    float4 v1 = *(const float4*)(x2h + (size_t)l * Hz + c0 + 8 * w + 4);
    xreg[0] = v0.x; xreg[1] = v0.y; xreg[2] = v0.z; xreg[3] = v0.w;
    xreg[4] = v1.x; xreg[5] = v1.y; xreg[6] = v1.z; xreg[7] = v1.w;
  }
  float wr[32];
  {
    const float* wp = W_rff + (size_t)(m * 32 + rloc) * Hz + kseg * 32;
    #pragma unroll
    for (int i = 0; i < 32; ++i) wr[i] = wp[i];
  }

  const float bu = bias[mycol];
  const float gu = gam[mycol];
  const float eu = eps[mycol];
  float hy = 0.f, hz = 0.f, zc = 0.f, zs = 0.f;
  hyf[0][u] = 0.f;
  if (u < 16) ((float4*)xb[0])[u] = ((const float4*)(x + (size_t)b * Lz * Iz))[u];
  __syncthreads();

  auto rff_acc = [&](const float* hsrc) {
    float acc = 0.f;
    const float4* hp = (const float4*)hsrc;
    #pragma unroll
    for (int i = 0; i < 8; ++i) {
      int q = kseg * 8 + i;
      float4 h4 = hp[q ^ ((q >> 3) & 7)];
      acc = fmaf(h4.x, wr[4 * i], acc);
      acc = fmaf(h4.y, wr[4 * i + 1], acc);
      acc = fmaf(h4.z, wr[4 * i + 2], acc);
      acc = fmaf(h4.w, wr[4 * i + 3], acc);
    }
    acc += __shfl_xor(acc, 1); acc += __shfl_xor(acc, 2);
    acc += __shfl_xor(acc, 4); acc += __shfl_xor(acc, 8);
    float sv, cv;
    __sincosf(acc, &sv, &cv);
    zc += cv; zs += sv;
  };

  for (int t = 0; t < Lz; ++t) {
    const int cur = t & 1, nxt = cur ^ 1;
    if (u < 16 && t + 1 < Lz)
      ((float4*)xb[nxt])[u] =
          ((const float4*)(x + ((size_t)b * Lz + (t + 1)) * Iz))[u];
    float hv[8];
    {
      const float4* hp = (const float4*)hyf[cur];
      int q0 = 2 * l, q1 = 2 * l + 1;
      float4 h0 = hp[q0 ^ ((q0 >> 3) & 7)];
      float4 h1 = hp[q1 ^ ((q1 >> 3) & 7)];
      hv[0] = h0.x; hv[1] = h0.y; hv[2] = h0.z; hv[3] = h0.w;
      hv[4] = h1.x; hv[5] = h1.y; hv[6] = h1.z; hv[7] = h1.w;
    }
    float a[8] = {0.f,0.f,0.f,0.f,0.f,0.f,0.f,0.f};
    #pragma unroll
    for (int r = 0; r < 8; ++r) {
      float h = hv[r];
      #pragma unroll
      for (int c = 0; c < 8; ++c) a[c] = fmaf(h, wreg[r][c], a[c]);
    }
    {
      float xv = xb[cur][l];
      #pragma unroll
      for (int c = 0; c < 8; ++c) a[c] = fmaf(xv, xreg[c], a[c]);
    }
    #pragma unroll
    for (int i = 0; i < 4; ++i) {
      float snd = (l & 1) ? a[i] : a[i + 4];
      float rcv = __shfl_xor(snd, 1);
      a[i] = ((l & 1) ? a[i + 4] : a[i]) + rcv;
    }
    #pragma unroll
    for (int i = 0; i < 2; ++i) {
      float snd = (l & 2) ? a[i] : a[i + 2];
      float rcv = __shfl_xor(snd, 2);
      a[i] = ((l & 2) ? a[i + 2] : a[i]) + rcv;
    }
    float s;
    {
      float snd = (l & 4) ? a[0] : a[1];
      float rcv = __shfl_xor(snd, 4);
      s = ((l & 4) ? a[1] : a[0]) + rcv;
    }
    s += __shfl_xor(s, 8); s += __shfl_xor(s, 16); s += __shfl_xor(s, 32);

    s += bu;
    float e2 = __expf(s + s);
    float pre = 1.f - 2.f * __builtin_amdgcn_rcpf(e2 + 1.f);
    float hzn = fmaf(DTz, pre - gu * hy - eu * hz, hz);
    hy = fmaf(DTz, hzn, hy);
    hz = hzn;

    const unsigned tag = (unsigned)(t + 1);
    u64* XA = Xb + ((size_t)nxt * Bz + b) * Hz;
    u64* YA = Yb + ((size_t)nxt * Bz + b) * Hz;

    if (l < 8) {
      u64 pv = packv(hy, tag);
      *(volatile u64*)(XA + mycol) = pv;
      __hip_atomic_store(YA + mycol, pv, __ATOMIC_RELAXED,
                         __HIP_MEMORY_SCOPE_AGENT);
      int q = mycol >> 2;
      hyf[nxt][((q ^ ((q >> 3) & 7)) << 2) | (mycol & 3)] = hy;
    }
    if (t > 0) rff_acc(hyf[cur]);
    if (w != m) {
      u64 v; int it = 0;
      for (;;) {
        v = *(volatile const u64*)(XA + u);
        if (tagok(v, tag)) break;
        if (it >= 2) {
          v = __hip_atomic_load(YA + u, __ATOMIC_RELAXED,
                                __HIP_MEMORY_SCOPE_AGENT);
          if (tagok(v, tag)) break;
        }
        if (++it > (1 << 20)) break;
      }
      int q = u >> 2;
      hyf[nxt][((q ^ ((q >> 3) & 7)) << 2) | (u & 3)] = unpackv(v);
    }
    __syncthreads();
  }

  rff_acc(hyf[0]);
  if (l < 8) out[(size_t)Bz * Hz + (size_t)b * Hz + mycol] = hy;
  if (kseg == 0) {
    const float sc = 0.0625f / 2048.f;
    out[(size_t)b * Hz + m * 32 + rloc] = zc * sc;
    out[(size_t)b * Hz + HALFz + m * 32 + rloc] = zs * sc;
  }
}

// ================= tertiary: single-block-per-batch (proven R1) =================
#define FMA4(P, S, W) do { (P).x = fmaf((S), (W).x, (P).x); (P).y = fmaf((S), (W).y, (P).y); \
                           (P).z = fmaf((S), (W).z, (P).z); (P).w = fmaf((S), (W).w, (P).w); } while(0)

__global__ __launch_bounds__(512) void coesn_scan_fb(
    const float* __restrict__ x, const float* __restrict__ x2h,
    const float* __restrict__ h2h, const float* __restrict__ bias,
    const float* __restrict__ gam, const float* __restrict__ eps,
    const float* __restrict__ W_rff, float* __restrict__ out) {
  const int b = blockIdx.x;
  const int u = threadIdx.x;
  __shared__ __align__(16) float hy_lds[Hz];
  __shared__ __align__(16) float x_lds[Iz];
  __shared__ float4 part[4][128];
  __shared__ float wx_lds[HALFz];

  float hy = 0.f, hz = 0.f, zsum = 0.f;
  const float bu = bias[u];
  const float gu = gam[u];
  const float eu = eps[u];

  const int kq = u >> 7;
  const int g  = u & 127;
  const int jj = u >> 2;
  const int ks = u & 3;

  const float4* __restrict__ H4 = (const float4*)h2h;
  const float4* __restrict__ X2 = (const float4*)x2h;
  const float4* __restrict__ W4 = (const float4*)W_rff;
  const float4* __restrict__ XG = (const float4*)x;
  const float4* hy4 = (const float4*)hy_lds;

  hy_lds[u] = 0.f;
  if (u < 16) ((float4*)x_lds)[u] = XG[(long)b * Lz * 16 + u];
  __syncthreads();

  for (int t = 0; t < Lz; ++t) {
    float4 p = make_float4(0.f, 0.f, 0.f, 0.f);
    {
      const float4* hp = (const float4*)&hy_lds[kq << 7];
      #pragma unroll 8
      for (int k4 = 0; k4 < 32; ++k4) {
        float4 hv = hp[k4];
        const float4* wr2 = &H4[(size_t)((kq << 7) + (k4 << 2)) * 128 + g];
        float4 w0 = wr2[0]; float4 w1 = wr2[128]; float4 w2 = wr2[256]; float4 w3 = wr2[384];
        FMA4(p, hv.x, w0); FMA4(p, hv.y, w1); FMA4(p, hv.z, w2); FMA4(p, hv.w, w3);
      }
      const float4* xp = (const float4*)&x_lds[kq << 4];
      #pragma unroll
      for (int k4 = 0; k4 < 4; ++k4) {
        float4 xv = xp[k4];
        const float4* wr2 = &X2[(size_t)((kq << 4) + (k4 << 2)) * 128 + g];
        float4 w0 = wr2[0]; float4 w1 = wr2[128]; float4 w2 = wr2[256]; float4 w3 = wr2[384];
        FMA4(p, xv.x, w0); FMA4(p, xv.y, w1); FMA4(p, xv.z, w2); FMA4(p, xv.w, w3);
      }
    }
    part[kq][g] = p;
    __syncthreads();
    {
      const float* pp = (const float*)part;
      float s = (pp[u] + pp[512 + u]) + (pp[1024 + u] + pp[1536 + u]);
      float pre = tanhf(s + bu);
      float hzn = fmaf(DTz, pre - gu * hy - eu * hz, hz);
      hy = fmaf(DTz, hzn, hy);
      hz = hzn;
      hy_lds[u] = hy;
      if (u < 16 && t + 1 < Lz)
        ((float4*)x_lds)[u] = XG[((long)b * Lz + (t + 1)) * 16 + u];
    }
    __syncthreads();
    {
      float4 acc0 = make_float4(0.f,0.f,0.f,0.f), acc1 = make_float4(0.f,0.f,0.f,0.f);
      #pragma unroll 4
      for (int it = 0; it < 32; ++it) {
        int k4 = (it << 2) + ks;
        float4 hv = hy4[k4];
        float4 w0 = W4[(size_t)jj * 128 + k4];
        float4 w1 = W4[(size_t)(jj + 128) * 128 + k4];
        acc0.x = fmaf(hv.x, w0.x, acc0.x); acc0.y = fmaf(hv.y, w0.y, acc0.y);
        acc0.z = fmaf(hv.z, w0.z, acc0.z); acc0.w = fmaf(hv.w, w0.w, acc0.w);
        acc1.x = fmaf(hv.x, w1.x, acc1.x); acc1.y = fmaf(hv.y, w1.y, acc1.y);
        acc1.z = fmaf(hv.z, w1.z, acc1.z); acc1.w = fmaf(hv.w, w1.w, acc1.w);
      }
      float a0 = (acc0.x + acc0.y) + (acc0.z + acc0.w);
      float a1 = (acc1.x + acc1.y) + (acc1.z + acc1.w);
      a0 += __shfl_xor(a0, 1); a0 += __shfl_xor(a0, 2);
      a1 += __shfl_xor(a1, 1); a1 += __shfl_xor(a1, 2);
      if (ks == 0) { wx_lds[jj] = a0; wx_lds[jj + 128] = a1; }
    }
    __syncthreads();
    {
      float v = wx_lds[u & 255];
      zsum += (u < HALFz) ? cosf(v) : sinf(v);
    }
  }
  out[(long)b * Hz + u] = zsum * (0.0625f / 2048.f);
  out[(long)Bz * Hz + (long)b * Hz + u] = hy;
}

extern "C" void kernel_launch(void* const* d_in, const int* in_sizes, int n_in,
                              void* d_out, int out_size, void* d_ws, size_t ws_size,
                              hipStream_t stream) {
  const float* x    = (const float*)d_in[0];
  const float* x2h  = (const float*)d_in[1];
  const float* h2h  = (const float*)d_in[2];
  const float* bias = (const float*)d_in[3];
  const float* gam  = (const float*)d_in[4];
  const float* eps  = (const float*)d_in[5];
  const float* wrff = (const float*)d_in[6];
  float* out = (float*)d_out;

  // ws: region0 256KB = primary Eb (2 parity x 32 grp x 512 u64);
  //     region0+region1 512KB = secondary Xb/Yb
  const size_t NEX = (size_t)2 * Bz * Hz;               // u64 per buffer
  const size_t WS_NEED = 2 * NEX * sizeof(u64);         // 512 KB
  if (ws_size >= WS_NEED) {
    u64* Eb = (u64*)d_ws;
    u64* Yb = Eb + NEX;
    hipMemsetAsync(d_ws, 0, WS_NEED, stream);

    void* args[] = { (void*)&x, (void*)&x2h, (void*)&h2h, (void*)&bias,
                     (void*)&gam, (void*)&eps, (void*)&wrff,
                     (void*)&Eb, (void*)&out };
    hipError_t e = hipLaunchCooperativeKernel((const void*)coesn_y1,
                                              dim3(Bz * NMEM), dim3(TPB),
                                              args, 0, stream);
    if (e == hipSuccess) return;

    void* args2[] = { (void*)&x, (void*)&x2h, (void*)&h2h, (void*)&bias,
                      (void*)&gam, (void*)&eps, (void*)&wrff,
                      (void*)&Eb, (void*)&Yb, (void*)&out };
    hipError_t e2 = hipLaunchCooperativeKernel((const void*)coesn_x2,
                                               dim3(Bz * NMEM), dim3(TPB),
                                               args2, 0, stream);
    if (e2 == hipSuccess) return;
  }
  coesn_scan_fb<<<Bz, 512, 0, stream>>>(x, x2h, h2h, bias, gam, eps, wrff, out);
}

// Round 12
// 3456.883 us; speedup vs baseline: 1.2844x; 1.2844x over previous
//
#include <hip/hip_runtime.h>
#include <math.h>

#define Bz 32
#define Lz 2048
#define Iz 64
#define Hz 512
#define HALFz 256
#define DTz 0.05f
#define NMEM 8
#define TPB 512

typedef unsigned long long u64;

__device__ __forceinline__ bool tagok(u64 v, unsigned tag) {
  u64 want = (u64)tag | ((u64)tag << 48);
  return ((v ^ want) & 0xFFFF00000000FFFFull) == 0ull;
}
__device__ __forceinline__ u64 packv(float f, unsigned tag) {
  return (u64)tag | ((u64)__float_as_uint(f) << 16) | ((u64)tag << 48);
}
__device__ __forceinline__ float unpackv(u64 v) {
  return __uint_as_float((unsigned)(v >> 16));
}

// ============ minimum-traffic exchange kernel (primary) ============
// Byte-identical to the proven R6 champion (3412us) EXCEPT the exchange:
//  - single buffer, single volatile u64 publish (volatile = sc0+sc1 = MALL-
//    coherent; tags self-validate; no Y duplicate, no spec pre-load).
//  - poll: s_sleep(1) first (lets the publish turn MALL-visible so the FIRST
//    load samples fresh data), then volatile load; on miss s_sleep(2) backoff.
// Rationale (R11 post-mortem): duration tracks MALL poll traffic almost
// linearly (+92MB FETCH <-> +1030us). R6 issues ~3 loads/thread/step (stale
// spec + retries + dead Y dupes); this issues ~1.1. Same RTT, less contention.
// Parity-2 reuse safety = R6's transitive-barrier argument (a block writing
// tag t+3 has received all tag t+2, implying every block finished step t+1,
// implying all tag t+1 polls completed -> overwrite safe).
// NOTE (R5 bug): rff_acc's shfl chain fully reduces wx into every lane of the
// 16-lane kseg group -> zc/zs complete per-lane; never re-reduce them.
__global__ __launch_bounds__(TPB, 2) void coesn_mt(
    const float* __restrict__ x, const float* __restrict__ x2h,
    const float* __restrict__ h2h, const float* __restrict__ bias,
    const float* __restrict__ gam, const float* __restrict__ eps,
    const float* __restrict__ W_rff, u64* __restrict__ Eb,
    float* __restrict__ out) {
  __shared__ __align__(16) float hyf[2][Hz];   // swizzled hy double buffer
  __shared__ __align__(16) float xb[2][Iz];    // x_t double buffer

  const int b  = blockIdx.x & 31;
  const int m  = blockIdx.x >> 5;
  const int u  = threadIdx.x;
  const int w  = u >> 6;          // wave id; owner-member of global col u
  const int l  = u & 63;
  const int c0 = m * 64;
  const int j  = ((l & 1) << 2) | (l & 2) | ((l >> 2) & 1);  // fold col map
  const int mycol = c0 + w * 8 + j;
  const int rloc = u >> 4, kseg = u & 15;

  // ---- weights into registers (one-time) ----
  float wreg[8][8];   // h2h[8l+r][c0+8w+c]
  {
    const float* hrow = h2h + (size_t)(8 * l) * Hz + c0 + 8 * w;
    #pragma unroll
    for (int r = 0; r < 8; ++r) {
      float4 v0 = *(const float4*)(hrow + (size_t)r * Hz);
      float4 v1 = *(const float4*)(hrow + (size_t)r * Hz + 4);
      wreg[r][0] = v0.x; wreg[r][1] = v0.y; wreg[r][2] = v0.z; wreg[r][3] = v0.w;
      wreg[r][4] = v1.x; wreg[r][5] = v1.y; wreg[r][6] = v1.z; wreg[r][7] = v1.w;
    }
  }
  float xreg[8];      // x2h[l][c0+8w+c]
  {
    float4 v0 = *(const float4*)(x2h + (size_t)l * Hz + c0 + 8 * w);
    float4 v1 = *(const float4*)(x2h + (size_t)l * Hz + c0 + 8 * w + 4);
    xreg[0] = v0.x; xreg[1] = v0.y; xreg[2] = v0.z; xreg[3] = v0.w;
    xreg[4] = v1.x; xreg[5] = v1.y; xreg[6] = v1.z; xreg[7] = v1.w;
  }
  float wr[32];       // W_rff[m*32+rloc][kseg*32 ..)
  {
    const float* wp = W_rff + (size_t)(m * 32 + rloc) * Hz + kseg * 32;
    #pragma unroll
    for (int i = 0; i < 32; ++i) wr[i] = wp[i];
  }

  const float bu = bias[mycol];
  const float gu = gam[mycol];
  const float eu = eps[mycol];
  float hy = 0.f, hz = 0.f, zc = 0.f, zs = 0.f;
  hyf[0][u] = 0.f;
  if (u < 16) ((float4*)xb[0])[u] = ((const float4*)(x + (size_t)b * Lz * Iz))[u];
  __syncthreads();

  auto rff_acc = [&](const float* hsrc) {
    float acc = 0.f;
    const float4* hp = (const float4*)hsrc;
    #pragma unroll
    for (int i = 0; i < 8; ++i) {
      int q = kseg * 8 + i;
      float4 h4 = hp[q ^ ((q >> 3) & 7)];
      acc = fmaf(h4.x, wr[4 * i], acc);
      acc = fmaf(h4.y, wr[4 * i + 1], acc);
      acc = fmaf(h4.z, wr[4 * i + 2], acc);
      acc = fmaf(h4.w, wr[4 * i + 3], acc);
    }
    acc += __shfl_xor(acc, 1); acc += __shfl_xor(acc, 2);
    acc += __shfl_xor(acc, 4); acc += __shfl_xor(acc, 8);
    float sv, cv;
    __sincosf(acc, &sv, &cv);
    zc += cv; zs += sv;   // complete per-lane across the 16-lane group
  };

  for (int t = 0; t < Lz; ++t) {
    const int cur = t & 1, nxt = cur ^ 1;

    // ---- x(t+1) prefetch ----
    if (u < 16 && t + 1 < Lz)
      ((float4*)xb[nxt])[u] =
          ((const float4*)(x + ((size_t)b * Lz + (t + 1)) * Iz))[u];

    // ---- matvec: lane covers K-rows [8l,8l+8) for cols c0+8w..+8 ----
    float hv[8];
    {
      const float4* hp = (const float4*)hyf[cur];
      int q0 = 2 * l, q1 = 2 * l + 1;
      float4 h0 = hp[q0 ^ ((q0 >> 3) & 7)];
      float4 h1 = hp[q1 ^ ((q1 >> 3) & 7)];
      hv[0] = h0.x; hv[1] = h0.y; hv[2] = h0.z; hv[3] = h0.w;
      hv[4] = h1.x; hv[5] = h1.y; hv[6] = h1.z; hv[7] = h1.w;
    }
    float a[8] = {0.f,0.f,0.f,0.f,0.f,0.f,0.f,0.f};
    #pragma unroll
    for (int r = 0; r < 8; ++r) {
      float h = hv[r];
      #pragma unroll
      for (int c = 0; c < 8; ++c) a[c] = fmaf(h, wreg[r][c], a[c]);
    }
    {
      float xv = xb[cur][l];
      #pragma unroll
      for (int c = 0; c < 8; ++c) a[c] = fmaf(xv, xreg[c], a[c]);
    }
    // ---- 10-shuffle fold: lane ends with full sum for col j(l) ----
    #pragma unroll
    for (int i = 0; i < 4; ++i) {
      float snd = (l & 1) ? a[i] : a[i + 4];
      float rcv = __shfl_xor(snd, 1);
      a[i] = ((l & 1) ? a[i + 4] : a[i]) + rcv;
    }
    #pragma unroll
    for (int i = 0; i < 2; ++i) {
      float snd = (l & 2) ? a[i] : a[i + 2];
      float rcv = __shfl_xor(snd, 2);
      a[i] = ((l & 2) ? a[i + 2] : a[i]) + rcv;
    }
    float s;
    {
      float snd = (l & 4) ? a[0] : a[1];
      float rcv = __shfl_xor(snd, 4);
      s = ((l & 4) ? a[1] : a[0]) + rcv;
    }
    s += __shfl_xor(s, 8); s += __shfl_xor(s, 16); s += __shfl_xor(s, 32);

    // ---- state update (divergence-free; redundant across lane-octs) ----
    s += bu;
    float e2 = __expf(s + s);
    float pre = 1.f - 2.f * __builtin_amdgcn_rcpf(e2 + 1.f);   // fast tanh
    float hzn = fmaf(DTz, pre - gu * hy - eu * hz, hz);
    hy = fmaf(DTz, hzn, hy);
    hz = hzn;

    const unsigned tag = (unsigned)(t + 1);
    u64* EA = Eb + ((size_t)nxt * Bz + b) * Hz;

    // ---- publish hy(t+1): single volatile u64 (MALL-coherent, tagged) ----
    if (l < 8) {
      *(volatile u64*)(EA + mycol) = packv(hy, tag);
      int q = mycol >> 2;
      hyf[nxt][((q ^ ((q >> 3) & 7)) << 2) | (mycol & 3)] = hy;   // local cols
    }

    // ---- RFF on hy(t) in the exchange shadow ----
    if (t > 0) rff_acc(hyf[cur]);

    // ---- poll remote column: sleep-first, minimal loads ----
    if (w != m) {
      __builtin_amdgcn_s_sleep(1);          // let publish turn MALL-visible
      u64 v; long it = 0;
      for (;;) {
        v = *(volatile const u64*)(EA + u);
        if (tagok(v, tag)) break;
        __builtin_amdgcn_s_sleep(2);        // 128cy backoff, cuts MALL traffic
        if (++it > (1 << 20)) break;        // safety bail (never in practice)
      }
      int q = u >> 2;
      hyf[nxt][((q ^ ((q >> 3) & 7)) << 2) | (u & 3)] = unpackv(v);
    }
    __syncthreads();
  }

  // final RFF term on hy(Lz) (loop covered hy(1)..hy(Lz-1)); Lz even -> [0]
  rff_acc(hyf[0]);

  if (l < 8) out[(size_t)Bz * Hz + (size_t)b * Hz + mycol] = hy;
  if (kseg == 0) {
    const float sc = 0.0625f / 2048.f;   // (1/sqrt(256)) / L
    out[(size_t)b * Hz + m * 32 + rloc] = zc * sc;
    out[(size_t)b * Hz + HALFz + m * 32 + rloc] = zs * sc;
  }
}

// ================= secondary: proven R6 kernel (3412us) =================
__global__ __launch_bounds__(TPB, 2) void coesn_x2(
    const float* __restrict__ x, const float* __restrict__ x2h,
    const float* __restrict__ h2h, const float* __restrict__ bias,
    const float* __restrict__ gam, const float* __restrict__ eps,
    const float* __restrict__ W_rff, u64* __restrict__ Xb,
    u64* __restrict__ Yb, float* __restrict__ out) {
  __shared__ __align__(16) float hyf[2][Hz];
  __shared__ __align__(16) float xb[2][Iz];

  const int b  = blockIdx.x & 31;
  const int m  = blockIdx.x >> 5;
  const int u  = threadIdx.x;
  const int w  = u >> 6;
  const int l  = u & 63;
  const int c0 = m * 64;
  const int j  = ((l & 1) << 2) | (l & 2) | ((l >> 2) & 1);
  const int mycol = c0 + w * 8 + j;
  const int rloc = u >> 4, kseg = u & 15;

  float wreg[8][8];
  {
    const float* hrow = h2h + (size_t)(8 * l) * Hz + c0 + 8 * w;
    #pragma unroll
    for (int r = 0; r < 8; ++r) {
      float4 v0 = *(const float4*)(hrow + (size_t)r * Hz);
      float4 v1 = *(const float4*)(hrow + (size_t)r * Hz + 4);
      wreg[r][0] = v0.x; wreg[r][1] = v0.y; wreg[r][2] = v0.z; wreg[r][3] = v0.w;
      wreg[r][4] = v1.x; wreg[r][5] = v1.y; wreg[r][6] = v1.z; wreg[r][7] = v1.w;
    }
  }
  float xreg[8];
  {
    float4 v0 = *(const float4*)(x2h + (size_t)l * Hz + c0 + 8 * w);
    float4 v1 = *(const float4*)(x2h + (size_t)l * Hz + c0 + 8 * w + 4);
    xreg[0] = v0.x; xreg[1] = v0.y; xreg[2] = v0.z; xreg[3] = v0.w;
    xreg[4] = v1.x; xreg[5] = v1.y; xreg[6] = v1.z; xreg[7] = v1.w;
  }
  float wr[32];
  {
    const float* wp = W_rff + (size_t)(m * 32 + rloc) * Hz + kseg * 32;
    #pragma unroll
    for (int i = 0; i < 32; ++i) wr[i] = wp[i];
  }

  const float bu = bias[mycol];
  const float gu = gam[mycol];
  const float eu = eps[mycol];
  float hy = 0.f, hz = 0.f, zc = 0.f, zs = 0.f;
  hyf[0][u] = 0.f;
  if (u < 16) ((float4*)xb[0])[u] = ((const float4*)(x + (size_t)b * Lz * Iz))[u];
  __syncthreads();

  auto rff_acc = [&](const float* hsrc) {
    float acc = 0.f;
    const float4* hp = (const float4*)hsrc;
    #pragma unroll
    for (int i = 0; i < 8; ++i) {
      int q = kseg * 8 + i;
      float4 h4 = hp[q ^ ((q >> 3) & 7)];
      acc = fmaf(h4.x, wr[4 * i], acc);
      acc = fmaf(h4.y, wr[4 * i + 1], acc);
      acc = fmaf(h4.z, wr[4 * i + 2], acc);
      acc = fmaf(h4.w, wr[4 * i + 3], acc);
    }
    acc += __shfl_xor(acc, 1); acc += __shfl_xor(acc, 2);
    acc += __shfl_xor(acc, 4); acc += __shfl_xor(acc, 8);
    float sv, cv;
    __sincosf(acc, &sv, &cv);
    zc += cv; zs += sv;
  };

  for (int t = 0; t < Lz; ++t) {
    const int cur = t & 1, nxt = cur ^ 1;
    if (u < 16 && t + 1 < Lz)
      ((float4*)xb[nxt])[u] =
          ((const float4*)(x + ((size_t)b * Lz + (t + 1)) * Iz))[u];
    float hv[8];
    {
      const float4* hp = (const float4*)hyf[cur];
      int q0 = 2 * l, q1 = 2 * l + 1;
      float4 h0 = hp[q0 ^ ((q0 >> 3) & 7)];
      float4 h1 = hp[q1 ^ ((q1 >> 3) & 7)];
      hv[0] = h0.x; hv[1] = h0.y; hv[2] = h0.z; hv[3] = h0.w;
      hv[4] = h1.x; hv[5] = h1.y; hv[6] = h1.z; hv[7] = h1.w;
    }
    float a[8] = {0.f,0.f,0.f,0.f,0.f,0.f,0.f,0.f};
    #pragma unroll
    for (int r = 0; r < 8; ++r) {
      float h = hv[r];
      #pragma unroll
      for (int c = 0; c < 8; ++c) a[c] = fmaf(h, wreg[r][c], a[c]);
    }
    {
      float xv = xb[cur][l];
      #pragma unroll
      for (int c = 0; c < 8; ++c) a[c] = fmaf(xv, xreg[c], a[c]);
    }
    #pragma unroll
    for (int i = 0; i < 4; ++i) {
      float snd = (l & 1) ? a[i] : a[i + 4];
      float rcv = __shfl_xor(snd, 1);
      a[i] = ((l & 1) ? a[i + 4] : a[i]) + rcv;
    }
    #pragma unroll
    for (int i = 0; i < 2; ++i) {
      float snd = (l & 2) ? a[i] : a[i + 2];
      float rcv = __shfl_xor(snd, 2);
      a[i] = ((l & 2) ? a[i + 2] : a[i]) + rcv;
    }
    float s;
    {
      float snd = (l & 4) ? a[0] : a[1];
      float rcv = __shfl_xor(snd, 4);
      s = ((l & 4) ? a[1] : a[0]) + rcv;
    }
    s += __shfl_xor(s, 8); s += __shfl_xor(s, 16); s += __shfl_xor(s, 32);

    s += bu;
    float e2 = __expf(s + s);
    float pre = 1.f - 2.f * __builtin_amdgcn_rcpf(e2 + 1.f);
    float hzn = fmaf(DTz, pre - gu * hy - eu * hz, hz);
    hy = fmaf(DTz, hzn, hy);
    hz = hzn;

    const unsigned tag = (unsigned)(t + 1);
    u64* XA = Xb + ((size_t)nxt * Bz + b) * Hz;
    u64* YA = Yb + ((size_t)nxt * Bz + b) * Hz;

    if (l < 8) {
      u64 pv = packv(hy, tag);
      *(volatile u64*)(XA + mycol) = pv;
      __hip_atomic_store(YA + mycol, pv, __ATOMIC_RELAXED,
                         __HIP_MEMORY_SCOPE_AGENT);
      int q = mycol >> 2;
      hyf[nxt][((q ^ ((q >> 3) & 7)) << 2) | (mycol & 3)] = hy;
    }
    if (t > 0) rff_acc(hyf[cur]);
    if (w != m) {
      u64 v; int it = 0;
      for (;;) {
        v = *(volatile const u64*)(XA + u);
        if (tagok(v, tag)) break;
        if (it >= 2) {
          v = __hip_atomic_load(YA + u, __ATOMIC_RELAXED,
                                __HIP_MEMORY_SCOPE_AGENT);
          if (tagok(v, tag)) break;
        }
        if (++it > (1 << 20)) break;
      }
      int q = u >> 2;
      hyf[nxt][((q ^ ((q >> 3) & 7)) << 2) | (u & 3)] = unpackv(v);
    }
    __syncthreads();
  }

  rff_acc(hyf[0]);
  if (l < 8) out[(size_t)Bz * Hz + (size_t)b * Hz + mycol] = hy;
  if (kseg == 0) {
    const float sc = 0.0625f / 2048.f;
    out[(size_t)b * Hz + m * 32 + rloc] = zc * sc;
    out[(size_t)b * Hz + HALFz + m * 32 + rloc] = zs * sc;
  }
}

// ================= tertiary: single-block-per-batch (proven R1) =================
#define FMA4(P, S, W) do { (P).x = fmaf((S), (W).x, (P).x); (P).y = fmaf((S), (W).y, (P).y); \
                           (P).z = fmaf((S), (W).z, (P).z); (P).w = fmaf((S), (W).w, (P).w); } while(0)

__global__ __launch_bounds__(512) void coesn_scan_fb(
    const float* __restrict__ x, const float* __restrict__ x2h,
    const float* __restrict__ h2h, const float* __restrict__ bias,
    const float* __restrict__ gam, const float* __restrict__ eps,
    const float* __restrict__ W_rff, float* __restrict__ out) {
  const int b = blockIdx.x;
  const int u = threadIdx.x;
  __shared__ __align__(16) float hy_lds[Hz];
  __shared__ __align__(16) float x_lds[Iz];
  __shared__ float4 part[4][128];
  __shared__ float wx_lds[HALFz];

  float hy = 0.f, hz = 0.f, zsum = 0.f;
  const float bu = bias[u];
  const float gu = gam[u];
  const float eu = eps[u];

  const int kq = u >> 7;
  const int g  = u & 127;
  const int jj = u >> 2;
  const int ks = u & 3;

  const float4* __restrict__ H4 = (const float4*)h2h;
  const float4* __restrict__ X2 = (const float4*)x2h;
  const float4* __restrict__ W4 = (const float4*)W_rff;
  const float4* __restrict__ XG = (const float4*)x;
  const float4* hy4 = (const float4*)hy_lds;

  hy_lds[u] = 0.f;
  if (u < 16) ((float4*)x_lds)[u] = XG[(long)b * Lz * 16 + u];
  __syncthreads();

  for (int t = 0; t < Lz; ++t) {
    float4 p = make_float4(0.f, 0.f, 0.f, 0.f);
    {
      const float4* hp = (const float4*)&hy_lds[kq << 7];
      #pragma unroll 8
      for (int k4 = 0; k4 < 32; ++k4) {
        float4 hv = hp[k4];
        const float4* wr2 = &H4[(size_t)((kq << 7) + (k4 << 2)) * 128 + g];
        float4 w0 = wr2[0]; float4 w1 = wr2[128]; float4 w2 = wr2[256]; float4 w3 = wr2[384];
        FMA4(p, hv.x, w0); FMA4(p, hv.y, w1); FMA4(p, hv.z, w2); FMA4(p, hv.w, w3);
      }
      const float4* xp = (const float4*)&x_lds[kq << 4];
      #pragma unroll
      for (int k4 = 0; k4 < 4; ++k4) {
        float4 xv = xp[k4];
        const float4* wr2 = &X2[(size_t)((kq << 4) + (k4 << 2)) * 128 + g];
        float4 w0 = wr2[0]; float4 w1 = wr2[128]; float4 w2 = wr2[256]; float4 w3 = wr2[384];
        FMA4(p, xv.x, w0); FMA4(p, xv.y, w1); FMA4(p, xv.z, w2); FMA4(p, xv.w, w3);
      }
    }
    part[kq][g] = p;
    __syncthreads();
    {
      const float* pp = (const float*)part;
      float s = (pp[u] + pp[512 + u]) + (pp[1024 + u] + pp[1536 + u]);
      float pre = tanhf(s + bu);
      float hzn = fmaf(DTz, pre - gu * hy - eu * hz, hz);
      hy = fmaf(DTz, hzn, hy);
      hz = hzn;
      hy_lds[u] = hy;
      if (u < 16 && t + 1 < Lz)
        ((float4*)x_lds)[u] = XG[((long)b * Lz + (t + 1)) * 16 + u];
    }
    __syncthreads();
    {
      float4 acc0 = make_float4(0.f,0.f,0.f,0.f), acc1 = make_float4(0.f,0.f,0.f,0.f);
      #pragma unroll 4
      for (int it = 0; it < 32; ++it) {
        int k4 = (it << 2) + ks;
        float4 hv = hy4[k4];
        float4 w0 = W4[(size_t)jj * 128 + k4];
        float4 w1 = W4[(size_t)(jj + 128) * 128 + k4];
        acc0.x = fmaf(hv.x, w0.x, acc0.x); acc0.y = fmaf(hv.y, w0.y, acc0.y);
        acc0.z = fmaf(hv.z, w0.z, acc0.z); acc0.w = fmaf(hv.w, w0.w, acc0.w);
        acc1.x = fmaf(hv.x, w1.x, acc1.x); acc1.y = fmaf(hv.y, w1.y, acc1.y);
        acc1.z = fmaf(hv.z, w1.z, acc1.z); acc1.w = fmaf(hv.w, w1.w, acc1.w);
      }
      float a0 = (acc0.x + acc0.y) + (acc0.z + acc0.w);
      float a1 = (acc1.x + acc1.y) + (acc1.z + acc1.w);
      a0 += __shfl_xor(a0, 1); a0 += __shfl_xor(a0, 2);
      a1 += __shfl_xor(a1, 1); a1 += __shfl_xor(a1, 2);
      if (ks == 0) { wx_lds[jj] = a0; wx_lds[jj + 128] = a1; }
    }
    __syncthreads();
    {
      float v = wx_lds[u & 255];
      zsum += (u < HALFz) ? cosf(v) : sinf(v);
    }
  }
  out[(long)b * Hz + u] = zsum * (0.0625f / 2048.f);
  out[(long)Bz * Hz + (long)b * Hz + u] = hy;
}

extern "C" void kernel_launch(void* const* d_in, const int* in_sizes, int n_in,
                              void* d_out, int out_size, void* d_ws, size_t ws_size,
                              hipStream_t stream) {
  const float* x    = (const float*)d_in[0];
  const float* x2h  = (const float*)d_in[1];
  const float* h2h  = (const float*)d_in[2];
  const float* bias = (const float*)d_in[3];
  const float* gam  = (const float*)d_in[4];
  const float* eps  = (const float*)d_in[5];
  const float* wrff = (const float*)d_in[6];
  float* out = (float*)d_out;

  // ws: [0,256K) Eb (primary; also Xb for secondary); [256K,512K) Yb (secondary)
  const size_t NEX = (size_t)2 * Bz * Hz;               // u64 per buffer
  const size_t WS_NEED = 2 * NEX * sizeof(u64);         // 512 KB
  if (ws_size >= WS_NEED) {
    u64* Eb = (u64*)d_ws;
    u64* Yb = Eb + NEX;
    hipMemsetAsync(d_ws, 0, WS_NEED, stream);

    void* args[] = { (void*)&x, (void*)&x2h, (void*)&h2h, (void*)&bias,
                     (void*)&gam, (void*)&eps, (void*)&wrff,
                     (void*)&Eb, (void*)&out };
    hipError_t e = hipLaunchCooperativeKernel((const void*)coesn_mt,
                                              dim3(Bz * NMEM), dim3(TPB),
                                              args, 0, stream);
    if (e == hipSuccess) return;

    void* args2[] = { (void*)&x, (void*)&x2h, (void*)&h2h, (void*)&bias,
                      (void*)&gam, (void*)&eps, (void*)&wrff,
                      (void*)&Eb, (void*)&Yb, (void*)&out };
    hipError_t e2 = hipLaunchCooperativeKernel((const void*)coesn_x2,
                                               dim3(Bz * NMEM), dim3(TPB),
                                               args2, 0, stream);
    if (e2 == hipSuccess) return;
  }
  coesn_scan_fb<<<Bz, 512, 0, stream>>>(x, x2h, h2h, bias, gam, eps, wrff, out);
}